// Round 13
// baseline (233.970 us; speedup 1.0000x reference)
//
#include <hip/hip_runtime.h>
#include <hip/hip_bf16.h>

// ---------------- problem constants ----------------
#define N_NODES 4096
#define NE      32768           // raw edges
#define E_TOT   (NE + N_NODES)  // + self loops = 36864
#define IN_FEAT 256
#define HID     64
#define IN_HEAD 64
#define F1      4096            // IN_HEAD*HID
#define OUT_HEAD 5
#define OUT_FEAT 128
#define F2      640             // OUT_HEAD*OUT_FEAT
#define NEG_SLOPE 0.2f
#define EPS_A   1e-16f

typedef __bf16 bf16;
typedef bf16 bf16x8 __attribute__((ext_vector_type(8)));
typedef bf16 bf16x4 __attribute__((ext_vector_type(4)));
typedef float f32x4 __attribute__((ext_vector_type(4)));

// async global->LDS, 16B per lane; lds base must be wave-uniform (m104/m108)
__device__ inline void async_cp16(bf16* lds, const bf16* g) {
    __builtin_amdgcn_global_load_lds(
        (const __attribute__((address_space(1))) unsigned int*)g,
        (__attribute__((address_space(3))) unsigned int*)lds, 16, 0, 0);
}

// ---------------- CSR build (parallel; hist lives inside prep_kernel) ------
__global__ void scan_kernel(const int* __restrict__ counts,
                            int* __restrict__ row_start, int* __restrict__ cursor) {
    __shared__ int part[256];
    __shared__ int pre[257];
    int t = threadIdx.x;
    int base = t * 16;
    int local[16];
    int s = 0;
#pragma unroll
    for (int i = 0; i < 16; ++i) { local[i] = s; s += counts[base + i]; }
    part[t] = s;
    __syncthreads();
    if (t == 0) {
        int r = 0;
        for (int i = 0; i < 256; ++i) { pre[i] = r; r += part[i]; }
        pre[256] = r;
    }
    __syncthreads();
    int off = pre[t];
#pragma unroll
    for (int i = 0; i < 16; ++i) {
        int v = off + local[i];
        row_start[base + i] = v;
        cursor[base + i] = v;
    }
    if (t == 0) row_start[N_NODES] = pre[256];
}

// srclist stores SOURCE NODE IDs (R11: kills es[e] indirection downstream)
__global__ void scatter_kernel(const int* __restrict__ esrc,
                               const int* __restrict__ edst,
                               int* cursor, int* __restrict__ srclist) {
    int e = blockIdx.x * 256 + threadIdx.x;
    if (e >= E_TOT) return;
    int d = (e < NE) ? edst[e] : (e - NE);
    int s = (e < NE) ? esrc[e] : (e - NE);
    int slot = atomicAdd(&cursor[d], 1);
    srclist[slot] = s;
}

// ------------- merged operand prep + CSR hist (R15) -------------------------
// tobf16(x) | W1^T | W2^T | att-fold | hist — all independent, one dispatch.
#define PB_X   512
#define PB_W1  1024
#define PB_W2  2560
#define PB_ATT 64
#define PB_TOT (PB_X + PB_W1 + PB_W2 + PB_ATT)      // 4160
#define PB_HIST 144                                  // ceil(E_TOT/256)
__global__ __launch_bounds__(256)
void prep_kernel(const float* __restrict__ x, bf16* __restrict__ xb,
                 const float* __restrict__ W1, bf16* __restrict__ W1T,
                 const float* __restrict__ W2, bf16* __restrict__ W2T,
                 const float* __restrict__ as1, const float* __restrict__ ad1,
                 bf16* __restrict__ w1s, bf16* __restrict__ w1d,
                 const int* __restrict__ edst, int* __restrict__ counts) {
    __shared__ float tile[32][33];
    int b = blockIdx.x, t = threadIdx.x;
    if (b < PB_X) {
        int i = b * 256 + t;
        f32x4 a = *(const f32x4*)(x + (size_t)i * 8);
        f32x4 c = *(const f32x4*)(x + (size_t)i * 8 + 4);
        bf16x8 r;
        r[0] = (bf16)a[0]; r[1] = (bf16)a[1]; r[2] = (bf16)a[2]; r[3] = (bf16)a[3];
        r[4] = (bf16)c[0]; r[5] = (bf16)c[1]; r[6] = (bf16)c[2]; r[7] = (bf16)c[3];
        *(bf16x8*)(xb + (size_t)i * 8) = r;
    } else if (b < PB_X + PB_W1 + PB_W2) {
        const float* S; bf16* D; int R, C, gx, gy;
        if (b < PB_X + PB_W1) {
            int bb = b - PB_X;                    // W1: 256 x 4096
            S = W1; D = W1T; R = IN_FEAT; C = F1;
            gx = bb % (F1 / 32); gy = bb / (F1 / 32);
        } else {
            int bb = b - PB_X - PB_W1;            // W2: 4096 x 640
            S = W2; D = W2T; R = F1; C = F2;
            gx = bb % (F2 / 32); gy = bb / (F2 / 32);
        }
        int tx = t & 31, ty = t >> 5;
        int c0 = gx * 32, r0 = gy * 32;
#pragma unroll
        for (int i = 0; i < 4; ++i)
            tile[ty + i * 8][tx] = S[(size_t)(r0 + ty + i * 8) * C + c0 + tx];
        __syncthreads();
#pragma unroll
        for (int i = 0; i < 4; ++i)
            D[(size_t)(c0 + ty + i * 8) * R + r0 + tx] = (bf16)tile[tx][ty + i * 8];
    } else if (b < PB_TOT) {
        int id = (b - PB_X - PB_W1 - PB_W2) * 256 + t;  // 16384 = 256k x 64h
        int k = id >> 6, h = id & 63;
        const float* wrow = W1 + (size_t)k * F1 + h * HID;
        const float* a1 = as1 + h * HID;
        const float* a2 = ad1 + h * HID;
        float s = 0.f, d = 0.f;
#pragma unroll 8
        for (int c = 0; c < HID; ++c) {
            float w = wrow[c];
            s += w * a1[c];
            d += w * a2[c];
        }
        w1s[id] = (bf16)s;
        w1d[id] = (bf16)d;
    } else {
        int e = (b - PB_TOT) * 256 + t;                 // hist
        if (e < E_TOT) {
            int d = (e < NE) ? edst[e] : (e - NE);
            atomicAdd(&counts[d], 1);
        }
    }
}

// ---------------- MFMA GEMM body, 128x64 tile (R17/R18) --------------------
// BM=128 BN=64 BK=64; XOR-swizzled LDS (0 conflicts, r4). BN=64 = the
// validated TLP lever for deep-K gemm2 (R17: -7.6us).
template <int NDIM, int KDIM, int SPLITK>
__device__ __forceinline__
void gemm64_body(const bf16* __restrict__ A, const bf16* __restrict__ BT,
                 bf16* __restrict__ C, int nb, int mb, int zb) {
    __shared__ bf16 As[128][64];
    __shared__ bf16 Bs[64][64];
    const int tid  = threadIdx.x;
    const int wave = tid >> 6, lane = tid & 63;
    const int quad = lane >> 4, lr = lane & 15;
    const int m0 = mb * 128, n0 = nb * 64;
    const int kchunk = KDIM / SPLITK;
    const int kbeg = zb * kchunk;
    const int wm = (wave >> 1) * 64;
    const int wn = (wave & 1) * 32;
    bf16* Cz = C + (size_t)zb * N_NODES * NDIM;

    const int srow = lane >> 3;
    const int scol = ((lane & 7) ^ srow) * 8;
    const int xk = lr & 7;

    f32x4 acc[4][2] = {};

    for (int kk = 0; kk < kchunk; kk += 64) {
        int k0 = kbeg + kk;
#pragma unroll
        for (int c = 0; c < 4; ++c) {               // A: 128 rows, 4/wave
            int r = wave * 32 + c * 8;
            async_cp16(&As[r][0], A + (size_t)(m0 + r + srow) * KDIM + k0 + scol);
        }
#pragma unroll
        for (int c = 0; c < 2; ++c) {               // B: 64 rows, 2/wave
            int r = wave * 16 + c * 8;
            async_cp16(&Bs[r][0], BT + (size_t)(n0 + r + srow) * KDIM + k0 + scol);
        }
        __syncthreads();

#pragma unroll
        for (int ks = 0; ks < 2; ++ks) {
            int ch = ((ks * 4 + quad) ^ xk) * 8;
            bf16x8 af[4], bfr[2];
#pragma unroll
            for (int mt = 0; mt < 4; ++mt)
                af[mt] = *(const bf16x8*)(&As[wm + mt * 16 + lr][ch]);
#pragma unroll
            for (int nt = 0; nt < 2; ++nt)
                bfr[nt] = *(const bf16x8*)(&Bs[wn + nt * 16 + lr][ch]);
#pragma unroll
            for (int mt = 0; mt < 4; ++mt)
#pragma unroll
                for (int nt = 0; nt < 2; ++nt)
                    acc[mt][nt] = __builtin_amdgcn_mfma_f32_16x16x32_bf16(
                        af[mt], bfr[nt], acc[mt][nt], 0, 0, 0);
        }
        __syncthreads();
    }

#pragma unroll
    for (int mt = 0; mt < 4; ++mt)
#pragma unroll
        for (int nt = 0; nt < 2; ++nt) {
            int row0 = m0 + wm + mt * 16 + quad * 4;
            int col = n0 + wn + nt * 16 + lr;
#pragma unroll
            for (int r = 0; r < 4; ++r)
                Cz[(size_t)(row0 + r) * NDIM + col] = (bf16)acc[mt][nt][r];
        }
}

// gemm2: BN=64, SPLITK=4, XCD-SWZ grid 1280 (R17 proven: -7.6us vs 128x128)
__global__ __launch_bounds__(256)
void gemm2_kernel(const bf16* __restrict__ A, const bf16* __restrict__ BT,
                  bf16* __restrict__ C) {
    int bid = blockIdx.x;
    int xx = bid & 7, q = bid >> 3;          // q in 0..159
    int gp = q / 10; int nb = q - gp * 10;   // nb 0..9 (64-col tiles)
    int g = gp * 8 + xx;                     // 0..127 = 32 mb x 4 zb
    int mb = g >> 2, zb = g & 3;
    gemm64_body<F2, F1, 4>(A, BT, C, nb, mb, zb);
}

// ------- layer-1 merged: gemm1 (2048 dbuf blocks) + gemv1 (1024) -----------
// R19: gemm1 has only 4 K-steps (K=256) — R15/R18 counters (MfmaUtil 7%,
// all pipes ~75% idle at occ 21-33%) say the per-K-step vmcnt(0)+barrier
// DRAIN is the critical path, and neither fatter (R16) nor thinner (R18)
// tiles moved it. Fix = T3 "minimum 2-phase": double-buffered LDS, stage
// t+1 issued BEFORE compute(t), raw s_barrier + explicit vmcnt(0) (not
// __syncthreads) so the prefetch's HBM latency hides under compute+TLP.
// Safety: every wave waits vmcnt(0) (its own stage loads done) before the
// barrier -> after barrier ALL stage loads are complete; buffer cur^1 is
// only rewritten after the barrier that follows its last read.
__global__ __launch_bounds__(256)
void layer1_kernel(const bf16* __restrict__ xb, const bf16* __restrict__ W1T,
                   bf16* __restrict__ H1,
                   const float* __restrict__ x,
                   const bf16* __restrict__ w1s, const bf16* __restrict__ w1d,
                   float* __restrict__ a_src, float* __restrict__ a_dst) {
    int bid = blockIdx.x;
    if (bid < 2048) {
        __shared__ bf16 As[2][128][64];
        __shared__ bf16 Bs[2][64][64];
        const int nb = bid & 63, mb = bid >> 6;
        const int tid  = threadIdx.x;
        const int wave = tid >> 6, lane = tid & 63;
        const int quad = lane >> 4, lr = lane & 15;
        const int m0 = mb * 128, n0 = nb * 64;
        const int wm = (wave >> 1) * 64;
        const int wn = (wave & 1) * 32;
        const int srow = lane >> 3;
        const int scol = ((lane & 7) ^ srow) * 8;
        const int xk = lr & 7;

        f32x4 acc[4][2] = {};

        auto STAGE = [&](int buf, int k0) {
#pragma unroll
            for (int c = 0; c < 4; ++c) {           // A: 128 rows, 4/wave
                int r = wave * 32 + c * 8;
                async_cp16(&As[buf][r][0],
                           xb + (size_t)(m0 + r + srow) * IN_FEAT + k0 + scol);
            }
#pragma unroll
            for (int c = 0; c < 2; ++c) {           // B: 64 rows, 2/wave
                int r = wave * 16 + c * 8;
                async_cp16(&Bs[buf][r][0],
                           W1T + (size_t)(n0 + r + srow) * IN_FEAT + k0 + scol);
            }
        };

        STAGE(0, 0);
        asm volatile("s_waitcnt vmcnt(0)" ::: "memory");
        __builtin_amdgcn_s_barrier();
        int cur = 0;
#pragma unroll
        for (int t = 0; t < 4; ++t) {
            if (t < 3) STAGE(cur ^ 1, (t + 1) * 64);    // prefetch next K-step
#pragma unroll
            for (int ks = 0; ks < 2; ++ks) {
                int ch = ((ks * 4 + quad) ^ xk) * 8;
                bf16x8 af[4], bfr[2];
#pragma unroll
                for (int mt = 0; mt < 4; ++mt)
                    af[mt] = *(const bf16x8*)(&As[cur][wm + mt * 16 + lr][ch]);
#pragma unroll
                for (int nt = 0; nt < 2; ++nt)
                    bfr[nt] = *(const bf16x8*)(&Bs[cur][wn + nt * 16 + lr][ch]);
#pragma unroll
                for (int mt = 0; mt < 4; ++mt)
#pragma unroll
                    for (int nt = 0; nt < 2; ++nt)
                        acc[mt][nt] = __builtin_amdgcn_mfma_f32_16x16x32_bf16(
                            af[mt], bfr[nt], acc[mt][nt], 0, 0, 0);
            }
            asm volatile("s_waitcnt vmcnt(0)" ::: "memory");  // next buf landed
            __builtin_amdgcn_s_barrier();
            cur ^= 1;
        }

#pragma unroll
        for (int mt = 0; mt < 4; ++mt)
#pragma unroll
            for (int nt = 0; nt < 2; ++nt) {
                int row0 = m0 + wm + mt * 16 + quad * 4;
                int col = n0 + wn + nt * 16 + lr;
#pragma unroll
                for (int r = 0; r < 4; ++r)
                    H1[(size_t)(row0 + r) * F1 + col] = (bf16)acc[mt][nt][r];
            }
    } else {
        int wave = threadIdx.x >> 6, lane = threadIdx.x & 63;
        int n = (bid - 2048) * 4 + wave;
        const float* xr = x + (size_t)n * IN_FEAT;
        float s = 0.f, d = 0.f;
        for (int k0 = 0; k0 < IN_FEAT; k0 += 4) {
            f32x4 xv = *(const f32x4*)(xr + k0);
#pragma unroll
            for (int j = 0; j < 4; ++j) {
                float xs = xv[j];
                s += xs * (float)w1s[(k0 + j) * IN_HEAD + lane];
                d += xs * (float)w1d[(k0 + j) * IN_HEAD + lane];
            }
        }
        a_src[n * IN_HEAD + lane] = s;
        a_dst[n * IN_HEAD + lane] = d;
    }
}

// ------- layer-1 aggregation, FEATURE-SLICED + XCD-PINNED ------------------
// grid = 4096 dst x 8 slices, 64 threads (1 wave). bid&7 = slice -> XCD:
// XCD x only touches H1 cols [512x,512x+512) = 4 MB = its L2 capacity.
// R9: single-pass online softmax (defer-rescale T13).
// R10: software pipeline broke the per-edge latency chain (47->~30us WIN).
// R11: srclist (2-level chain). R12: depth-4 a_src/H1, slack-2 srclist.
// Explicit named rotation regs (rule #20).
__global__ __launch_bounds__(64)
void agg1_kernel(const int* __restrict__ row_start,
                 const int* __restrict__ srclist,
                 const float* __restrict__ a_src, const float* __restrict__ a_dst,
                 const bf16* __restrict__ H1, const float* __restrict__ b1,
                 bf16* __restrict__ h_elu) {
    int bid = blockIdx.x;
    int c = bid & 7;            // feature slice / XCD
    int d = bid >> 3;           // dst node
    int lane = threadIdx.x;
    int gh = c * 8 + (lane >> 3);   // global head for this lane
    int beg = row_start[d], deg = row_start[d + 1] - beg;
    float adst = a_dst[d * IN_HEAD + gh];
    int fbase = c * 512 + lane * 8;
    const float* asg = a_src + gh;

    // clamped prefetch (deg >= 1 always; repeats hit L1/L2, harmless)
    auto SL = [&](int i) { return srclist[beg + (i < deg ? i : deg - 1)]; };

    // ---- pipeline prologue: 4 la/v stages in flight, 2 s-regs of slack ----
    int s0 = SL(0), s1 = SL(1), s2 = SL(2), s3 = SL(3);
    float la0 = asg[(size_t)s0 * IN_HEAD];
    bf16x8 v0 = *(const bf16x8*)(H1 + (size_t)s0 * F1 + fbase);
    float la1 = asg[(size_t)s1 * IN_HEAD];
    bf16x8 v1 = *(const bf16x8*)(H1 + (size_t)s1 * F1 + fbase);
    float la2 = asg[(size_t)s2 * IN_HEAD];
    bf16x8 v2 = *(const bf16x8*)(H1 + (size_t)s2 * F1 + fbase);
    float la3 = asg[(size_t)s3 * IN_HEAD];
    bf16x8 v3 = *(const bf16x8*)(H1 + (size_t)s3 * F1 + fbase);
    int s4 = SL(4), s5 = SL(5);

    float m = -1e30f, den = 0.f;
    float acc[8] = {};
    for (int i = 0; i < deg; ++i) {
        // stage issues (independent of this iteration's compute):
        int sn = SL(i + 6);                              // srclist, slack 2
        float la4 = asg[(size_t)s4 * IN_HEAD];           // edge i+4
        bf16x8 v4 = *(const bf16x8*)(H1 + (size_t)s4 * F1 + fbase);

        // compute edge i (operands loaded 4 iterations ago)
        float l = la0 + adst;
        l = l > 0.f ? l : NEG_SLOPE * l;
        if (l > m + 12.f) {                  // deferred rescale (rare)
            float r = __expf(m - l);         // m=-1e30 -> r=0 zeroes init
            den *= r;
#pragma unroll
            for (int k = 0; k < 8; ++k) acc[k] *= r;
            m = l;
        }
        float w = __expf(l - m);             // bounded by e^12
        den += w;
#pragma unroll
        for (int k = 0; k < 8; ++k) acc[k] += w * (float)v0[k];

        // rotate pipeline registers
        la0 = la1; v0 = v1;
        la1 = la2; v1 = v2;
        la2 = la3; v2 = v3;
        la3 = la4; v3 = v4;
        s4 = s5; s5 = sn;
    }
    float dinv = 1.f / (den + EPS_A);

    bf16x8 o;
#pragma unroll
    for (int j = 0; j < 8; ++j) {
        float v = acc[j] * dinv + b1[fbase + j];
        o[j] = (bf16)(v > 0.f ? v : (__expf(v) - 1.f));   // ELU
    }
    *(bf16x8*)(h_elu + (size_t)d * F1 + fbase) = o;
}

// ------- fold 4 bf16 z-partials -> H2 fp32, fused att2 dots ----------------
__global__ __launch_bounds__(192)
void fold2_kernel(const bf16* __restrict__ Hp,
                  const float* __restrict__ as2, const float* __restrict__ ad2,
                  float* __restrict__ H2,
                  float* __restrict__ a_src, float* __restrict__ a_dst) {
    int n = blockIdx.x, t = threadIdx.x;
    if (t >= 160) return;
    int h = t >> 5;
    f32x4 sum = {};
#pragma unroll
    for (int z = 0; z < 4; ++z) {
        bf16x4 v = *(const bf16x4*)(Hp + (size_t)z * N_NODES * F2 + (size_t)n * F2 + t * 4);
        sum[0] += (float)v[0]; sum[1] += (float)v[1];
        sum[2] += (float)v[2]; sum[3] += (float)v[3];
    }
    *(f32x4*)(H2 + (size_t)n * F2 + t * 4) = sum;
    f32x4 ws = *(const f32x4*)(as2 + t * 4);
    f32x4 wd = *(const f32x4*)(ad2 + t * 4);
    float s = sum[0] * ws[0] + sum[1] * ws[1] + sum[2] * ws[2] + sum[3] * ws[3];
    float d = sum[0] * wd[0] + sum[1] * wd[1] + sum[2] * wd[2] + sum[3] * wd[3];
#pragma unroll
    for (int o = 1; o <= 16; o <<= 1) {
        s += __shfl_xor(s, o);
        d += __shfl_xor(d, o);
    }
    if ((t & 31) == 0) {
        a_src[n * OUT_HEAD + h] = s;
        a_dst[n * OUT_HEAD + h] = d;
    }
}

// ------- layer-2 softmax stats: thread per (dst,head) over CSR ----------
// defer-rescale (exact — offset cancels in beta) + depth-2 prefetch;
// zeroes beta[id] (replaces memset; runs before beta_kernel). [R13, kept]
__global__ void stats2_kernel(const int* __restrict__ row_start,
                              const int* __restrict__ srclist,
                              const float* __restrict__ a_src,
                              const float* __restrict__ a_dst,
                              float* __restrict__ m2, float* __restrict__ dinv2,
                              float* __restrict__ beta) {
    int id = blockIdx.x * 256 + threadIdx.x;
    if (id >= N_NODES * OUT_HEAD) return;
    beta[id] = 0.f;
    int d = id / OUT_HEAD, h = id - d * OUT_HEAD;
    int beg = row_start[d], deg = row_start[d + 1] - beg;
    float adst = a_dst[id];
    auto SL = [&](int i) { return srclist[beg + (i < deg ? i : deg - 1)]; };
    int s0 = SL(0), s1 = SL(1);
    float la0 = a_src[s0 * OUT_HEAD + h];
    float m = -1e30f, den = 0.f;
    for (int i = 0; i < deg; ++i) {
        int s2 = SL(i + 2);
        float la1 = a_src[s1 * OUT_HEAD + h];
        float l = la0 + adst;
        l = l > 0.f ? l : NEG_SLOPE * l;
        if (l > m + 12.f) { den *= __expf(m - l); m = l; }
        den += __expf(l - m);
        la0 = la1; s1 = s2;
    }
    m2[id] = m;
    dinv2[id] = 1.f / (den + EPS_A);
}

// ------- beta[s][h] = sum over edges with src s of alpha2[e][h] ----------
// edge-parallel (184k threads). Also zeroes acc_out/ticket for wsum
// (stream order guarantees completion before wsum launches). [R13, kept]
__global__ void beta_kernel(const int* __restrict__ es, const int* __restrict__ ed,
                            const float* __restrict__ a_src, const float* __restrict__ a_dst,
                            const float* __restrict__ m2, const float* __restrict__ dinv2,
                            float* __restrict__ beta,
                            float* __restrict__ acc_out, int* __restrict__ ticket) {
    int id = blockIdx.x * 256 + threadIdx.x;
    if (id < 8 * OUT_FEAT) acc_out[id] = 0.f;
    else if (id == 8 * OUT_FEAT) *ticket = 0;
    if (id >= E_TOT * OUT_HEAD) return;
    int e = id / OUT_HEAD, h = id - e * OUT_HEAD;
    int s = (e < NE) ? es[e] : (e - NE);
    int d = (e < NE) ? ed[e] : (e - NE);
    float l = a_src[s * OUT_HEAD + h] + a_dst[d * OUT_HEAD + h];
    l = l > 0.f ? l : NEG_SLOPE * l;
    float alpha = __expf(l - m2[d * OUT_HEAD + h]) * dinv2[d * OUT_HEAD + h];
    atomicAdd(&beta[s * OUT_HEAD + h], alpha);
}

// ------- total[c] = sum_s sum_h beta[s,h]H2[s,h*128+c]; 8-way stripes -------
// tanh fused via last-block ticket (device-scope atomics; coherent cross-XCD
// readback via atomicAdd(p, 0.f) — G16-safe). Verified R12.
__global__ __launch_bounds__(256)
void wsum_kernel(const float* __restrict__ H2, const float* __restrict__ beta,
                 float* __restrict__ acc_out, const float* __restrict__ b2,
                 float* __restrict__ out, int* __restrict__ ticket) {
    __shared__ float buf[F2];
    __shared__ int lastblk;
    int t = threadIdx.x;
    int n0 = blockIdx.x * 32;
    int h = t >> 5;
    float a0 = 0.f, a1 = 0.f, a2 = 0.f, a3 = 0.f;
    if (t < 160) {
        for (int i = 0; i < 32; ++i) {
            int s = n0 + i;
            float bh = beta[s * OUT_HEAD + h];
            f32x4 v = *(const f32x4*)(H2 + (size_t)s * F2 + t * 4);
            a0 += bh * v[0]; a1 += bh * v[1];
            a2 += bh * v[2]; a3 += bh * v[3];
        }
        buf[t * 4 + 0] = a0; buf[t * 4 + 1] = a1;
        buf[t * 4 + 2] = a2; buf[t * 4 + 3] = a3;
    }
    __syncthreads();
    if (t < OUT_FEAT) {
        float s = 0.f;
#pragma unroll
        for (int hh = 0; hh < OUT_HEAD; ++hh) s += buf[hh * OUT_FEAT + t];
        atomicAdd(&acc_out[(blockIdx.x & 7) * OUT_FEAT + t], s);
    }
    __syncthreads();                      // barrier drains this block's atomics
    if (t == 0) {
        __threadfence();
        lastblk = (atomicAdd(ticket, 1) == (int)gridDim.x - 1);
    }
    __syncthreads();
    if (lastblk && t < OUT_FEAT) {
        float tot = 0.f;
#pragma unroll
        for (int k = 0; k < 8; ++k)
            tot += atomicAdd(&acc_out[k * OUT_FEAT + t], 0.0f);  // coherent read
        out[t] = tanhf(tot * (1.f / (OUT_HEAD * (float)N_NODES)) + b2[t]);
    }
}

// ---------------- launch ----------------
extern "C" void kernel_launch(void* const* d_in, const int* in_sizes, int n_in,
                              void* d_out, int out_size, void* d_ws, size_t ws_size,
                              hipStream_t stream) {
    const float* x        = (const float*)d_in[0];
    const int*   ei       = (const int*)d_in[1];
    const float* W1       = (const float*)d_in[2];
    const float* att_src1 = (const float*)d_in[3];
    const float* att_dst1 = (const float*)d_in[4];
    const float* b1       = (const float*)d_in[5];
    const float* W2       = (const float*)d_in[6];
    const float* att_src2 = (const float*)d_in[7];
    const float* att_dst2 = (const float*)d_in[8];
    const float* b2       = (const float*)d_in[9];
    float* out = (float*)d_out;

    const int* esrc = ei;
    const int* edst = ei + NE;

    // workspace carve (~110 MB)
    char* p = (char*)d_ws;
    auto bump = [&](size_t bytes) {
        void* r = (void*)p;
        p += (bytes + 255) & ~(size_t)255;
        return r;
    };
    bf16*  H1     = (bf16*)bump((size_t)N_NODES * F1 * 2);        // 32 MB
    bf16*  h_elu  = (bf16*)bump((size_t)N_NODES * F1 * 2);        // 32 MB
    bf16*  Hp     = (bf16*)bump((size_t)4 * N_NODES * F2 * 2);    // 21 MB (4 z-partials)
    float* H2     = (float*)bump((size_t)N_NODES * F2 * 4);       // 10.5 MB
    bf16*  xb     = (bf16*)bump((size_t)N_NODES * IN_FEAT * 2);   // 2 MB
    bf16*  W1T    = (bf16*)bump((size_t)F1 * IN_FEAT * 2);        // 2 MB
    bf16*  W2T    = (bf16*)bump((size_t)F2 * F1 * 2);             // 5 MB
    bf16*  w1s    = (bf16*)bump((size_t)IN_FEAT * IN_HEAD * 2);
    bf16*  w1d    = (bf16*)bump((size_t)IN_FEAT * IN_HEAD * 2);
    float* a_src1 = (float*)bump((size_t)N_NODES * IN_HEAD * 4);
    float* a_dst1 = (float*)bump((size_t)N_NODES * IN_HEAD * 4);
    float* a_src2 = (float*)bump((size_t)N_NODES * OUT_HEAD * 4);
    float* a_dst2 = (float*)bump((size_t)N_NODES * OUT_HEAD * 4);
    float* m2     = (float*)bump((size_t)N_NODES * OUT_HEAD * 4);
    float* dinv2  = (float*)bump((size_t)N_NODES * OUT_HEAD * 4);
    int*   row_start = (int*)bump((N_NODES + 1) * 4);
    int*   cursor  = (int*)bump(N_NODES * 4);
    int*   srclist = (int*)bump(E_TOT * 4);
    int*   counts  = (int*)bump(N_NODES * 4);
    float* beta    = (float*)bump((size_t)N_NODES * OUT_HEAD * 4);
    float* acc_out = (float*)bump((size_t)8 * OUT_FEAT * 4);
    int*   ticket  = (int*)bump(4);

    // counts zero (16 KB) then prep(+hist) -> scan -> scatter
    hipMemsetAsync(counts, 0, N_NODES * 4, stream);
    prep_kernel<<<PB_TOT + PB_HIST, 256, 0, stream>>>(
        x, xb, W1, W1T, W2, W2T, att_src1, att_dst1, w1s, w1d, edst, counts);
    scan_kernel<<<1, 256, 0, stream>>>(counts, row_start, cursor);
    scatter_kernel<<<(E_TOT + 255) / 256, 256, 0, stream>>>(
        esrc, edst, cursor, srclist);

    // layer 1: gemm1 (BN=64 dbuf, 2048 blocks) + gemv1 in one dispatch
    layer1_kernel<<<3072, 256, 0, stream>>>(
        xb, W1T, H1, x, w1s, w1d, a_src1, a_dst1);
    agg1_kernel<<<N_NODES * 8, 64, 0, stream>>>(
        row_start, srclist, a_src1, a_dst1, H1, b1, h_elu);

    // layer 2: BN=64 SPLITK=4 z-partials (grid 1280, ~5 blocks/CU) + fold
    gemm2_kernel<<<1280, 256, 0, stream>>>(h_elu, W2T, Hp);
    fold2_kernel<<<N_NODES, 192, 0, stream>>>(
        Hp, att_src2, att_dst2, H2, a_src2, a_dst2);
    stats2_kernel<<<(N_NODES * OUT_HEAD + 255) / 256, 256, 0, stream>>>(
        row_start, srclist, a_src2, a_dst2, m2, dinv2, beta);
    beta_kernel<<<(E_TOT * OUT_HEAD + 255) / 256, 256, 0, stream>>>(
        esrc, edst, a_src2, a_dst2, m2, dinv2, beta, acc_out, ticket);
    wsum_kernel<<<N_NODES / 32, 256, 0, stream>>>(
        H2, beta, acc_out, b2, out, ticket);
}

// Round 14
// 223.868 us; speedup vs baseline: 1.0451x; 1.0451x over previous
//
#include <hip/hip_runtime.h>
#include <hip/hip_bf16.h>

// ---------------- problem constants ----------------
#define N_NODES 4096
#define NE      32768           // raw edges
#define E_TOT   (NE + N_NODES)  // + self loops = 36864
#define IN_FEAT 256
#define HID     64
#define IN_HEAD 64
#define F1      4096            // IN_HEAD*HID
#define OUT_HEAD 5
#define OUT_FEAT 128
#define F2      640             // OUT_HEAD*OUT_FEAT
#define NEG_SLOPE 0.2f
#define EPS_A   1e-16f

typedef __bf16 bf16;
typedef bf16 bf16x8 __attribute__((ext_vector_type(8)));
typedef bf16 bf16x4 __attribute__((ext_vector_type(4)));
typedef float f32x4 __attribute__((ext_vector_type(4)));

// async global->LDS, 16B per lane; lds base must be wave-uniform (m104/m108)
__device__ inline void async_cp16(bf16* lds, const bf16* g) {
    __builtin_amdgcn_global_load_lds(
        (const __attribute__((address_space(1))) unsigned int*)g,
        (__attribute__((address_space(3))) unsigned int*)lds, 16, 0, 0);
}

// ---------------- CSR build (parallel; hist lives inside prep_kernel) ------
__global__ void scan_kernel(const int* __restrict__ counts,
                            int* __restrict__ row_start, int* __restrict__ cursor) {
    __shared__ int part[256];
    __shared__ int pre[257];
    int t = threadIdx.x;
    int base = t * 16;
    int local[16];
    int s = 0;
#pragma unroll
    for (int i = 0; i < 16; ++i) { local[i] = s; s += counts[base + i]; }
    part[t] = s;
    __syncthreads();
    if (t == 0) {
        int r = 0;
        for (int i = 0; i < 256; ++i) { pre[i] = r; r += part[i]; }
        pre[256] = r;
    }
    __syncthreads();
    int off = pre[t];
#pragma unroll
    for (int i = 0; i < 16; ++i) {
        int v = off + local[i];
        row_start[base + i] = v;
        cursor[base + i] = v;
    }
    if (t == 0) row_start[N_NODES] = pre[256];
}

// srclist stores SOURCE NODE IDs (R11: kills es[e] indirection downstream)
__global__ void scatter_kernel(const int* __restrict__ esrc,
                               const int* __restrict__ edst,
                               int* cursor, int* __restrict__ srclist) {
    int e = blockIdx.x * 256 + threadIdx.x;
    if (e >= E_TOT) return;
    int d = (e < NE) ? edst[e] : (e - NE);
    int s = (e < NE) ? esrc[e] : (e - NE);
    int slot = atomicAdd(&cursor[d], 1);
    srclist[slot] = s;
}

// ------------- merged operand prep + CSR hist (R15) -------------------------
// tobf16(x) | W1^T | W2^T | att-fold | hist — all independent, one dispatch.
#define PB_X   512
#define PB_W1  1024
#define PB_W2  2560
#define PB_ATT 64
#define PB_TOT (PB_X + PB_W1 + PB_W2 + PB_ATT)      // 4160
#define PB_HIST 144                                  // ceil(E_TOT/256)
__global__ __launch_bounds__(256)
void prep_kernel(const float* __restrict__ x, bf16* __restrict__ xb,
                 const float* __restrict__ W1, bf16* __restrict__ W1T,
                 const float* __restrict__ W2, bf16* __restrict__ W2T,
                 const float* __restrict__ as1, const float* __restrict__ ad1,
                 bf16* __restrict__ w1s, bf16* __restrict__ w1d,
                 const int* __restrict__ edst, int* __restrict__ counts) {
    __shared__ float tile[32][33];
    int b = blockIdx.x, t = threadIdx.x;
    if (b < PB_X) {
        int i = b * 256 + t;
        f32x4 a = *(const f32x4*)(x + (size_t)i * 8);
        f32x4 c = *(const f32x4*)(x + (size_t)i * 8 + 4);
        bf16x8 r;
        r[0] = (bf16)a[0]; r[1] = (bf16)a[1]; r[2] = (bf16)a[2]; r[3] = (bf16)a[3];
        r[4] = (bf16)c[0]; r[5] = (bf16)c[1]; r[6] = (bf16)c[2]; r[7] = (bf16)c[3];
        *(bf16x8*)(xb + (size_t)i * 8) = r;
    } else if (b < PB_X + PB_W1 + PB_W2) {
        const float* S; bf16* D; int R, C, gx, gy;
        if (b < PB_X + PB_W1) {
            int bb = b - PB_X;                    // W1: 256 x 4096
            S = W1; D = W1T; R = IN_FEAT; C = F1;
            gx = bb % (F1 / 32); gy = bb / (F1 / 32);
        } else {
            int bb = b - PB_X - PB_W1;            // W2: 4096 x 640
            S = W2; D = W2T; R = F1; C = F2;
            gx = bb % (F2 / 32); gy = bb / (F2 / 32);
        }
        int tx = t & 31, ty = t >> 5;
        int c0 = gx * 32, r0 = gy * 32;
#pragma unroll
        for (int i = 0; i < 4; ++i)
            tile[ty + i * 8][tx] = S[(size_t)(r0 + ty + i * 8) * C + c0 + tx];
        __syncthreads();
#pragma unroll
        for (int i = 0; i < 4; ++i)
            D[(size_t)(c0 + ty + i * 8) * R + r0 + tx] = (bf16)tile[tx][ty + i * 8];
    } else if (b < PB_TOT) {
        int id = (b - PB_X - PB_W1 - PB_W2) * 256 + t;  // 16384 = 256k x 64h
        int k = id >> 6, h = id & 63;
        const float* wrow = W1 + (size_t)k * F1 + h * HID;
        const float* a1 = as1 + h * HID;
        const float* a2 = ad1 + h * HID;
        float s = 0.f, d = 0.f;
#pragma unroll 8
        for (int c = 0; c < HID; ++c) {
            float w = wrow[c];
            s += w * a1[c];
            d += w * a2[c];
        }
        w1s[id] = (bf16)s;
        w1d[id] = (bf16)d;
    } else {
        int e = (b - PB_TOT) * 256 + t;                 // hist
        if (e < E_TOT) {
            int d = (e < NE) ? edst[e] : (e - NE);
            atomicAdd(&counts[d], 1);
        }
    }
}

// ---------------- gemm2: BN=64, SPLITK=4, XCD-SWZ (R17 proven) -------------
// BM=128 BN=64 BK=64; XOR-swizzled LDS (0 conflicts, r4). Grid 1280 ->
// ~5 blocks/CU covers the per-K-step barrier drains (-7.6us vs 128x128).
// N-split adds ZERO HBM bytes (vs SPLITK=8's +42MB, R14).
__global__ __launch_bounds__(256)
void gemm2_kernel(const bf16* __restrict__ A, const bf16* __restrict__ BT,
                  bf16* __restrict__ C) {
    __shared__ bf16 As[128][64];
    __shared__ bf16 Bs[64][64];
    const int tid  = threadIdx.x;
    const int wave = tid >> 6, lane = tid & 63;
    const int quad = lane >> 4, lr = lane & 15;
    int bid = blockIdx.x;
    int xx = bid & 7, q = bid >> 3;          // q in 0..159
    int gp = q / 10; int nb = q - gp * 10;   // nb 0..9 (64-col tiles)
    int g = gp * 8 + xx;                     // 0..127 = 32 mb x 4 zb
    int mb = g >> 2, zb = g & 3;
    const int m0 = mb * 128, n0 = nb * 64;
    const int kchunk = F1 / 4;
    const int kbeg = zb * kchunk;
    const int wm = (wave >> 1) * 64;
    const int wn = (wave & 1) * 32;
    bf16* Cz = C + (size_t)zb * N_NODES * F2;

    const int srow = lane >> 3;
    const int scol = ((lane & 7) ^ srow) * 8;
    const int xk = lr & 7;

    f32x4 acc[4][2] = {};

    for (int kk = 0; kk < kchunk; kk += 64) {
        int k0 = kbeg + kk;
#pragma unroll
        for (int c = 0; c < 4; ++c) {               // A: 128 rows, 4/wave
            int r = wave * 32 + c * 8;
            async_cp16(&As[r][0], A + (size_t)(m0 + r + srow) * F1 + k0 + scol);
        }
#pragma unroll
        for (int c = 0; c < 2; ++c) {               // B: 64 rows, 2/wave
            int r = wave * 16 + c * 8;
            async_cp16(&Bs[r][0], BT + (size_t)(n0 + r + srow) * F1 + k0 + scol);
        }
        __syncthreads();

#pragma unroll
        for (int ks = 0; ks < 2; ++ks) {
            int ch = ((ks * 4 + quad) ^ xk) * 8;
            bf16x8 af[4], bfr[2];
#pragma unroll
            for (int mt = 0; mt < 4; ++mt)
                af[mt] = *(const bf16x8*)(&As[wm + mt * 16 + lr][ch]);
#pragma unroll
            for (int nt = 0; nt < 2; ++nt)
                bfr[nt] = *(const bf16x8*)(&Bs[wn + nt * 16 + lr][ch]);
#pragma unroll
            for (int mt = 0; mt < 4; ++mt)
#pragma unroll
                for (int nt = 0; nt < 2; ++nt)
                    acc[mt][nt] = __builtin_amdgcn_mfma_f32_16x16x32_bf16(
                        af[mt], bfr[nt], acc[mt][nt], 0, 0, 0);
        }
        __syncthreads();
    }

#pragma unroll
    for (int mt = 0; mt < 4; ++mt)
#pragma unroll
        for (int nt = 0; nt < 2; ++nt) {
            int row0 = m0 + wm + mt * 16 + quad * 4;
            int col = n0 + wn + nt * 16 + lr;
#pragma unroll
            for (int r = 0; r < 4; ++r)
                Cz[(size_t)(row0 + r) * F2 + col] = (bf16)acc[mt][nt][r];
        }
}

// ------- layer-1 merged: gemm1 (1024 128x128 blocks) + gemv1 (1024) --------
// gemm half = R17's proven 128x128 form (best of all 4 measured variants:
// 45.0 vs 46.2 BN=64 vs 48.5 dbuf vs regression fat).
// R20 gemv half: each wave used to read the ENTIRE w1s+w1d (64 KB) from L2
// -> 4096 waves x 64 KB = 266 MB L2 traffic, L1-thrashing latency. Now the
// block stages both tables into the SAME 32 KB smem the gemm branch uses
// (2 chunks of 128 k-rows), and lanes read 2B from LDS (2 lanes/bank =
// conflict-free). Table traffic drops to 66 MB (once per block).
__global__ __launch_bounds__(256)
void layer1_kernel(const bf16* __restrict__ xb, const bf16* __restrict__ W1T,
                   bf16* __restrict__ H1,
                   const float* __restrict__ x,
                   const bf16* __restrict__ w1s, const bf16* __restrict__ w1d,
                   float* __restrict__ a_src, float* __restrict__ a_dst) {
    __shared__ bf16 smem[2][128][64];       // 32 KB, shared by both branches
    int bid = blockIdx.x;
    const int tid = threadIdx.x;
    if (bid < 1024) {
        // ---- gemm1: H1 = xb @ W1T^T, 128x128 tile ----
        bf16 (*As)[64] = smem[0];
        bf16 (*Bs)[64] = smem[1];
        const int wave = tid >> 6, lane = tid & 63;
        const int quad = lane >> 4, lr = lane & 15;
        const int nb = bid & 31, mb = bid >> 5;
        const int m0 = mb * 128, n0 = nb * 128;
        const int wm = (wave >> 1) * 64;
        const int wn = (wave & 1) * 64;
        const int srow = lane >> 3;
        const int scol = ((lane & 7) ^ srow) * 8;
        const int xk = lr & 7;

        f32x4 acc[4][4] = {};

        for (int k0 = 0; k0 < IN_FEAT; k0 += 64) {
#pragma unroll
            for (int c = 0; c < 4; ++c) {
                int r = wave * 32 + c * 8;
                async_cp16(&As[r][0], xb  + (size_t)(m0 + r + srow) * IN_FEAT + k0 + scol);
                async_cp16(&Bs[r][0], W1T + (size_t)(n0 + r + srow) * IN_FEAT + k0 + scol);
            }
            __syncthreads();

#pragma unroll
            for (int ks = 0; ks < 2; ++ks) {
                int ch = ((ks * 4 + quad) ^ xk) * 8;
                bf16x8 af[4], bfr[4];
#pragma unroll
                for (int mt = 0; mt < 4; ++mt)
                    af[mt] = *(const bf16x8*)(&As[wm + mt * 16 + lr][ch]);
#pragma unroll
                for (int nt = 0; nt < 4; ++nt)
                    bfr[nt] = *(const bf16x8*)(&Bs[wn + nt * 16 + lr][ch]);
#pragma unroll
                for (int mt = 0; mt < 4; ++mt)
#pragma unroll
                    for (int nt = 0; nt < 4; ++nt)
                        acc[mt][nt] = __builtin_amdgcn_mfma_f32_16x16x32_bf16(
                            af[mt], bfr[nt], acc[mt][nt], 0, 0, 0);
            }
            __syncthreads();
        }

#pragma unroll
        for (int mt = 0; mt < 4; ++mt)
#pragma unroll
            for (int nt = 0; nt < 4; ++nt) {
                int row0 = m0 + wm + mt * 16 + quad * 4;
                int col = n0 + wn + nt * 16 + lr;
#pragma unroll
                for (int r = 0; r < 4; ++r)
                    H1[(size_t)(row0 + r) * F1 + col] = (bf16)acc[mt][nt][r];
            }
    } else {
        // ---- gemv1: a_src/a_dst dots, LDS-staged tables ----
        bf16* sws = &smem[0][0][0];          // 16 KB: 128 k-rows of w1s
        bf16* swd = &smem[1][0][0];          // 16 KB: 128 k-rows of w1d
        int wave = tid >> 6, lane = tid & 63;
        int n = (bid - 1024) * 4 + wave;
        const float* xr = x + (size_t)n * IN_FEAT;
        float s = 0.f, d = 0.f;
#pragma unroll
        for (int c = 0; c < 2; ++c) {        // two 128-k chunks
            __syncthreads();                 // protect prior chunk's readers
#pragma unroll
            for (int i = 0; i < 4; ++i) {    // 1024 bf16x8 per table, 256 thr
                int v = i * 256 + tid;
                ((bf16x8*)sws)[v] = ((const bf16x8*)w1s)[c * 1024 + v];
                ((bf16x8*)swd)[v] = ((const bf16x8*)w1d)[c * 1024 + v];
            }
            __syncthreads();
            for (int k0 = 0; k0 < 128; k0 += 4) {
                f32x4 xv = *(const f32x4*)(xr + c * 128 + k0);
#pragma unroll
                for (int j = 0; j < 4; ++j) {
                    float xs = xv[j];
                    s += xs * (float)sws[(k0 + j) * IN_HEAD + lane];
                    d += xs * (float)swd[(k0 + j) * IN_HEAD + lane];
                }
            }
        }
        a_src[n * IN_HEAD + lane] = s;
        a_dst[n * IN_HEAD + lane] = d;
    }
}

// ------- layer-1 aggregation, FEATURE-SLICED + XCD-PINNED ------------------
// grid = 4096 dst x 8 slices, 64 threads (1 wave). bid&7 = slice -> XCD:
// XCD x only touches H1 cols [512x,512x+512) = 4 MB = its L2 capacity.
// R9: single-pass online softmax (defer-rescale T13).
// R10: software pipeline broke the per-edge latency chain (47->~30us WIN).
// R11: srclist (2-level chain). R12: depth-4 a_src/H1, slack-2 srclist.
// Explicit named rotation regs (rule #20).
__global__ __launch_bounds__(64)
void agg1_kernel(const int* __restrict__ row_start,
                 const int* __restrict__ srclist,
                 const float* __restrict__ a_src, const float* __restrict__ a_dst,
                 const bf16* __restrict__ H1, const float* __restrict__ b1,
                 bf16* __restrict__ h_elu) {
    int bid = blockIdx.x;
    int c = bid & 7;            // feature slice / XCD
    int d = bid >> 3;           // dst node
    int lane = threadIdx.x;
    int gh = c * 8 + (lane >> 3);   // global head for this lane
    int beg = row_start[d], deg = row_start[d + 1] - beg;
    float adst = a_dst[d * IN_HEAD + gh];
    int fbase = c * 512 + lane * 8;
    const float* asg = a_src + gh;

    // clamped prefetch (deg >= 1 always; repeats hit L1/L2, harmless)
    auto SL = [&](int i) { return srclist[beg + (i < deg ? i : deg - 1)]; };

    // ---- pipeline prologue: 4 la/v stages in flight, 2 s-regs of slack ----
    int s0 = SL(0), s1 = SL(1), s2 = SL(2), s3 = SL(3);
    float la0 = asg[(size_t)s0 * IN_HEAD];
    bf16x8 v0 = *(const bf16x8*)(H1 + (size_t)s0 * F1 + fbase);
    float la1 = asg[(size_t)s1 * IN_HEAD];
    bf16x8 v1 = *(const bf16x8*)(H1 + (size_t)s1 * F1 + fbase);
    float la2 = asg[(size_t)s2 * IN_HEAD];
    bf16x8 v2 = *(const bf16x8*)(H1 + (size_t)s2 * F1 + fbase);
    float la3 = asg[(size_t)s3 * IN_HEAD];
    bf16x8 v3 = *(const bf16x8*)(H1 + (size_t)s3 * F1 + fbase);
    int s4 = SL(4), s5 = SL(5);

    float m = -1e30f, den = 0.f;
    float acc[8] = {};
    for (int i = 0; i < deg; ++i) {
        // stage issues (independent of this iteration's compute):
        int sn = SL(i + 6);                              // srclist, slack 2
        float la4 = asg[(size_t)s4 * IN_HEAD];           // edge i+4
        bf16x8 v4 = *(const bf16x8*)(H1 + (size_t)s4 * F1 + fbase);

        // compute edge i (operands loaded 4 iterations ago)
        float l = la0 + adst;
        l = l > 0.f ? l : NEG_SLOPE * l;
        if (l > m + 12.f) {                  // deferred rescale (rare)
            float r = __expf(m - l);         // m=-1e30 -> r=0 zeroes init
            den *= r;
#pragma unroll
            for (int k = 0; k < 8; ++k) acc[k] *= r;
            m = l;
        }
        float w = __expf(l - m);             // bounded by e^12
        den += w;
#pragma unroll
        for (int k = 0; k < 8; ++k) acc[k] += w * (float)v0[k];

        // rotate pipeline registers
        la0 = la1; v0 = v1;
        la1 = la2; v1 = v2;
        la2 = la3; v2 = v3;
        la3 = la4; v3 = v4;
        s4 = s5; s5 = sn;
    }
    float dinv = 1.f / (den + EPS_A);

    bf16x8 o;
#pragma unroll
    for (int j = 0; j < 8; ++j) {
        float v = acc[j] * dinv + b1[fbase + j];
        o[j] = (bf16)(v > 0.f ? v : (__expf(v) - 1.f));   // ELU
    }
    *(bf16x8*)(h_elu + (size_t)d * F1 + fbase) = o;
}

// ------- fold 4 bf16 z-partials -> H2 fp32, fused att2 dots ----------------
__global__ __launch_bounds__(192)
void fold2_kernel(const bf16* __restrict__ Hp,
                  const float* __restrict__ as2, const float* __restrict__ ad2,
                  float* __restrict__ H2,
                  float* __restrict__ a_src, float* __restrict__ a_dst) {
    int n = blockIdx.x, t = threadIdx.x;
    if (t >= 160) return;
    int h = t >> 5;
    f32x4 sum = {};
#pragma unroll
    for (int z = 0; z < 4; ++z) {
        bf16x4 v = *(const bf16x4*)(Hp + (size_t)z * N_NODES * F2 + (size_t)n * F2 + t * 4);
        sum[0] += (float)v[0]; sum[1] += (float)v[1];
        sum[2] += (float)v[2]; sum[3] += (float)v[3];
    }
    *(f32x4*)(H2 + (size_t)n * F2 + t * 4) = sum;
    f32x4 ws = *(const f32x4*)(as2 + t * 4);
    f32x4 wd = *(const f32x4*)(ad2 + t * 4);
    float s = sum[0] * ws[0] + sum[1] * ws[1] + sum[2] * ws[2] + sum[3] * ws[3];
    float d = sum[0] * wd[0] + sum[1] * wd[1] + sum[2] * wd[2] + sum[3] * wd[3];
#pragma unroll
    for (int o = 1; o <= 16; o <<= 1) {
        s += __shfl_xor(s, o);
        d += __shfl_xor(d, o);
    }
    if ((t & 31) == 0) {
        a_src[n * OUT_HEAD + h] = s;
        a_dst[n * OUT_HEAD + h] = d;
    }
}

// ------- layer-2 softmax stats: thread per (dst,head) over CSR ----------
// defer-rescale (exact — offset cancels in beta) + depth-2 prefetch;
// zeroes beta[id] (replaces memset; runs before beta_kernel). [R13, kept]
__global__ void stats2_kernel(const int* __restrict__ row_start,
                              const int* __restrict__ srclist,
                              const float* __restrict__ a_src,
                              const float* __restrict__ a_dst,
                              float* __restrict__ m2, float* __restrict__ dinv2,
                              float* __restrict__ beta) {
    int id = blockIdx.x * 256 + threadIdx.x;
    if (id >= N_NODES * OUT_HEAD) return;
    beta[id] = 0.f;
    int d = id / OUT_HEAD, h = id - d * OUT_HEAD;
    int beg = row_start[d], deg = row_start[d + 1] - beg;
    float adst = a_dst[id];
    auto SL = [&](int i) { return srclist[beg + (i < deg ? i : deg - 1)]; };
    int s0 = SL(0), s1 = SL(1);
    float la0 = a_src[s0 * OUT_HEAD + h];
    float m = -1e30f, den = 0.f;
    for (int i = 0; i < deg; ++i) {
        int s2 = SL(i + 2);
        float la1 = a_src[s1 * OUT_HEAD + h];
        float l = la0 + adst;
        l = l > 0.f ? l : NEG_SLOPE * l;
        if (l > m + 12.f) { den *= __expf(m - l); m = l; }
        den += __expf(l - m);
        la0 = la1; s1 = s2;
    }
    m2[id] = m;
    dinv2[id] = 1.f / (den + EPS_A);
}

// ------- beta[s][h] = sum over edges with src s of alpha2[e][h] ----------
// edge-parallel (184k threads). Also zeroes acc_out/ticket for wsum
// (stream order guarantees completion before wsum launches). [R13, kept]
__global__ void beta_kernel(const int* __restrict__ es, const int* __restrict__ ed,
                            const float* __restrict__ a_src, const float* __restrict__ a_dst,
                            const float* __restrict__ m2, const float* __restrict__ dinv2,
                            float* __restrict__ beta,
                            float* __restrict__ acc_out, int* __restrict__ ticket) {
    int id = blockIdx.x * 256 + threadIdx.x;
    if (id < 8 * OUT_FEAT) acc_out[id] = 0.f;
    else if (id == 8 * OUT_FEAT) *ticket = 0;
    if (id >= E_TOT * OUT_HEAD) return;
    int e = id / OUT_HEAD, h = id - e * OUT_HEAD;
    int s = (e < NE) ? es[e] : (e - NE);
    int d = (e < NE) ? ed[e] : (e - NE);
    float l = a_src[s * OUT_HEAD + h] + a_dst[d * OUT_HEAD + h];
    l = l > 0.f ? l : NEG_SLOPE * l;
    float alpha = __expf(l - m2[d * OUT_HEAD + h]) * dinv2[d * OUT_HEAD + h];
    atomicAdd(&beta[s * OUT_HEAD + h], alpha);
}

// ------- total[c] = sum_s sum_h beta[s,h]H2[s,h*128+c]; 8-way stripes -------
// tanh fused via last-block ticket (device-scope atomics; coherent cross-XCD
// readback via atomicAdd(p, 0.f) — G16-safe). Verified R12.
__global__ __launch_bounds__(256)
void wsum_kernel(const float* __restrict__ H2, const float* __restrict__ beta,
                 float* __restrict__ acc_out, const float* __restrict__ b2,
                 float* __restrict__ out, int* __restrict__ ticket) {
    __shared__ float buf[F2];
    __shared__ int lastblk;
    int t = threadIdx.x;
    int n0 = blockIdx.x * 32;
    int h = t >> 5;
    float a0 = 0.f, a1 = 0.f, a2 = 0.f, a3 = 0.f;
    if (t < 160) {
        for (int i = 0; i < 32; ++i) {
            int s = n0 + i;
            float bh = beta[s * OUT_HEAD + h];
            f32x4 v = *(const f32x4*)(H2 + (size_t)s * F2 + t * 4);
            a0 += bh * v[0]; a1 += bh * v[1];
            a2 += bh * v[2]; a3 += bh * v[3];
        }
        buf[t * 4 + 0] = a0; buf[t * 4 + 1] = a1;
        buf[t * 4 + 2] = a2; buf[t * 4 + 3] = a3;
    }
    __syncthreads();
    if (t < OUT_FEAT) {
        float s = 0.f;
#pragma unroll
        for (int hh = 0; hh < OUT_HEAD; ++hh) s += buf[hh * OUT_FEAT + t];
        atomicAdd(&acc_out[(blockIdx.x & 7) * OUT_FEAT + t], s);
    }
    __syncthreads();                      // barrier drains this block's atomics
    if (t == 0) {
        __threadfence();
        lastblk = (atomicAdd(ticket, 1) == (int)gridDim.x - 1);
    }
    __syncthreads();
    if (lastblk && t < OUT_FEAT) {
        float tot = 0.f;
#pragma unroll
        for (int k = 0; k < 8; ++k)
            tot += atomicAdd(&acc_out[k * OUT_FEAT + t], 0.0f);  // coherent read
        out[t] = tanhf(tot * (1.f / (OUT_HEAD * (float)N_NODES)) + b2[t]);
    }
}

// ---------------- launch ----------------
extern "C" void kernel_launch(void* const* d_in, const int* in_sizes, int n_in,
                              void* d_out, int out_size, void* d_ws, size_t ws_size,
                              hipStream_t stream) {
    const float* x        = (const float*)d_in[0];
    const int*   ei       = (const int*)d_in[1];
    const float* W1       = (const float*)d_in[2];
    const float* att_src1 = (const float*)d_in[3];
    const float* att_dst1 = (const float*)d_in[4];
    const float* b1       = (const float*)d_in[5];
    const float* W2       = (const float*)d_in[6];
    const float* att_src2 = (const float*)d_in[7];
    const float* att_dst2 = (const float*)d_in[8];
    const float* b2       = (const float*)d_in[9];
    float* out = (float*)d_out;

    const int* esrc = ei;
    const int* edst = ei + NE;

    // workspace carve (~110 MB)
    char* p = (char*)d_ws;
    auto bump = [&](size_t bytes) {
        void* r = (void*)p;
        p += (bytes + 255) & ~(size_t)255;
        return r;
    };
    bf16*  H1     = (bf16*)bump((size_t)N_NODES * F1 * 2);        // 32 MB
    bf16*  h_elu  = (bf16*)bump((size_t)N_NODES * F1 * 2);        // 32 MB
    bf16*  Hp     = (bf16*)bump((size_t)4 * N_NODES * F2 * 2);    // 21 MB (4 z-partials)
    float* H2     = (float*)bump((size_t)N_NODES * F2 * 4);       // 10.5 MB
    bf16*  xb     = (bf16*)bump((size_t)N_NODES * IN_FEAT * 2);   // 2 MB
    bf16*  W1T    = (bf16*)bump((size_t)F1 * IN_FEAT * 2);        // 2 MB
    bf16*  W2T    = (bf16*)bump((size_t)F2 * F1 * 2);             // 5 MB
    bf16*  w1s    = (bf16*)bump((size_t)IN_FEAT * IN_HEAD * 2);
    bf16*  w1d    = (bf16*)bump((size_t)IN_FEAT * IN_HEAD * 2);
    float* a_src1 = (float*)bump((size_t)N_NODES * IN_HEAD * 4);
    float* a_dst1 = (float*)bump((size_t)N_NODES * IN_HEAD * 4);
    float* a_src2 = (float*)bump((size_t)N_NODES * OUT_HEAD * 4);
    float* a_dst2 = (float*)bump((size_t)N_NODES * OUT_HEAD * 4);
    float* m2     = (float*)bump((size_t)N_NODES * OUT_HEAD * 4);
    float* dinv2  = (float*)bump((size_t)N_NODES * OUT_HEAD * 4);
    int*   row_start = (int*)bump((N_NODES + 1) * 4);
    int*   cursor  = (int*)bump(N_NODES * 4);
    int*   srclist = (int*)bump(E_TOT * 4);
    int*   counts  = (int*)bump(N_NODES * 4);
    float* beta    = (float*)bump((size_t)N_NODES * OUT_HEAD * 4);
    float* acc_out = (float*)bump((size_t)8 * OUT_FEAT * 4);
    int*   ticket  = (int*)bump(4);

    // counts zero (16 KB) then prep(+hist) -> scan -> scatter
    hipMemsetAsync(counts, 0, N_NODES * 4, stream);
    prep_kernel<<<PB_TOT + PB_HIST, 256, 0, stream>>>(
        x, xb, W1, W1T, W2, W2T, att_src1, att_dst1, w1s, w1d, edst, counts);
    scan_kernel<<<1, 256, 0, stream>>>(counts, row_start, cursor);
    scatter_kernel<<<(E_TOT + 255) / 256, 256, 0, stream>>>(
        esrc, edst, cursor, srclist);

    // layer 1: gemm1 (128x128, 1024 blocks) + gemv1 (LDS-staged, 1024)
    layer1_kernel<<<2048, 256, 0, stream>>>(
        xb, W1T, H1, x, w1s, w1d, a_src1, a_dst1);
    agg1_kernel<<<N_NODES * 8, 64, 0, stream>>>(
        row_start, srclist, a_src1, a_dst1, H1, b1, h_elu);

    // layer 2: BN=64 SPLITK=4 z-partials (grid 1280, ~5 blocks/CU) + fold
    gemm2_kernel<<<1280, 256, 0, stream>>>(h_elu, W2T, Hp);
    fold2_kernel<<<N_NODES, 192, 0, stream>>>(
        Hp, att_src2, att_dst2, H2, a_src2, a_dst2);
    stats2_kernel<<<(N_NODES * OUT_HEAD + 255) / 256, 256, 0, stream>>>(
        row_start, srclist, a_src2, a_dst2, m2, dinv2, beta);
    beta_kernel<<<(E_TOT * OUT_HEAD + 255) / 256, 256, 0, stream>>>(
        esrc, edst, a_src2, a_dst2, m2, dinv2, beta, acc_out, ticket);
    wsum_kernel<<<N_NODES / 32, 256, 0, stream>>>(
        H2, beta, acc_out, b2, out, ticket);
}

// Round 16
// 223.118 us; speedup vs baseline: 1.0486x; 1.0034x over previous
//
#include <hip/hip_runtime.h>
#include <hip/hip_bf16.h>

// ---------------- problem constants ----------------
#define N_NODES 4096
#define NE      32768           // raw edges
#define E_TOT   (NE + N_NODES)  // + self loops = 36864
#define IN_FEAT 256
#define HID     64
#define IN_HEAD 64
#define F1      4096            // IN_HEAD*HID
#define OUT_HEAD 5
#define OUT_FEAT 128
#define F2      640             // OUT_HEAD*OUT_FEAT
#define NEG_SLOPE 0.2f
#define EPS_A   1e-16f

typedef __bf16 bf16;
typedef bf16 bf16x8 __attribute__((ext_vector_type(8)));
typedef bf16 bf16x4 __attribute__((ext_vector_type(4)));
typedef float f32x4 __attribute__((ext_vector_type(4)));

// async global->LDS, 16B per lane; lds base must be wave-uniform (m104/m108)
__device__ inline void async_cp16(bf16* lds, const bf16* g) {
    __builtin_amdgcn_global_load_lds(
        (const __attribute__((address_space(1))) unsigned int*)g,
        (__attribute__((address_space(3))) unsigned int*)lds, 16, 0, 0);
}

// ---------------- CSR build (parallel; hist lives inside prep_kernel) ------
__global__ void scan_kernel(const int* __restrict__ counts,
                            int* __restrict__ row_start, int* __restrict__ cursor) {
    __shared__ int part[256];
    __shared__ int pre[257];
    int t = threadIdx.x;
    int base = t * 16;
    int local[16];
    int s = 0;
#pragma unroll
    for (int i = 0; i < 16; ++i) { local[i] = s; s += counts[base + i]; }
    part[t] = s;
    __syncthreads();
    if (t == 0) {
        int r = 0;
        for (int i = 0; i < 256; ++i) { pre[i] = r; r += part[i]; }
        pre[256] = r;
    }
    __syncthreads();
    int off = pre[t];
#pragma unroll
    for (int i = 0; i < 16; ++i) {
        int v = off + local[i];
        row_start[base + i] = v;
        cursor[base + i] = v;
    }
    if (t == 0) row_start[N_NODES] = pre[256];
}

// srclist stores SOURCE NODE IDs (R11: kills es[e] indirection downstream)
__global__ void scatter_kernel(const int* __restrict__ esrc,
                               const int* __restrict__ edst,
                               int* cursor, int* __restrict__ srclist) {
    int e = blockIdx.x * 256 + threadIdx.x;
    if (e >= E_TOT) return;
    int d = (e < NE) ? edst[e] : (e - NE);
    int s = (e < NE) ? esrc[e] : (e - NE);
    int slot = atomicAdd(&cursor[d], 1);
    srclist[slot] = s;
}

// ------------- merged operand prep + CSR hist (R15) -------------------------
// tobf16(x) | W1^T | W2^T | att-fold | hist — all independent, one dispatch.
#define PB_X   512
#define PB_W1  1024
#define PB_W2  2560
#define PB_ATT 64
#define PB_TOT (PB_X + PB_W1 + PB_W2 + PB_ATT)      // 4160
#define PB_HIST 144                                  // ceil(E_TOT/256)
__global__ __launch_bounds__(256)
void prep_kernel(const float* __restrict__ x, bf16* __restrict__ xb,
                 const float* __restrict__ W1, bf16* __restrict__ W1T,
                 const float* __restrict__ W2, bf16* __restrict__ W2T,
                 const float* __restrict__ as1, const float* __restrict__ ad1,
                 bf16* __restrict__ w1s, bf16* __restrict__ w1d,
                 const int* __restrict__ edst, int* __restrict__ counts) {
    __shared__ float tile[32][33];
    int b = blockIdx.x, t = threadIdx.x;
    if (b < PB_X) {
        int i = b * 256 + t;
        f32x4 a = *(const f32x4*)(x + (size_t)i * 8);
        f32x4 c = *(const f32x4*)(x + (size_t)i * 8 + 4);
        bf16x8 r;
        r[0] = (bf16)a[0]; r[1] = (bf16)a[1]; r[2] = (bf16)a[2]; r[3] = (bf16)a[3];
        r[4] = (bf16)c[0]; r[5] = (bf16)c[1]; r[6] = (bf16)c[2]; r[7] = (bf16)c[3];
        *(bf16x8*)(xb + (size_t)i * 8) = r;
    } else if (b < PB_X + PB_W1 + PB_W2) {
        const float* S; bf16* D; int R, C, gx, gy;
        if (b < PB_X + PB_W1) {
            int bb = b - PB_X;                    // W1: 256 x 4096
            S = W1; D = W1T; R = IN_FEAT; C = F1;
            gx = bb % (F1 / 32); gy = bb / (F1 / 32);
        } else {
            int bb = b - PB_X - PB_W1;            // W2: 4096 x 640
            S = W2; D = W2T; R = F1; C = F2;
            gx = bb % (F2 / 32); gy = bb / (F2 / 32);
        }
        int tx = t & 31, ty = t >> 5;
        int c0 = gx * 32, r0 = gy * 32;
#pragma unroll
        for (int i = 0; i < 4; ++i)
            tile[ty + i * 8][tx] = S[(size_t)(r0 + ty + i * 8) * C + c0 + tx];
        __syncthreads();
#pragma unroll
        for (int i = 0; i < 4; ++i)
            D[(size_t)(c0 + ty + i * 8) * R + r0 + tx] = (bf16)tile[tx][ty + i * 8];
    } else if (b < PB_TOT) {
        int id = (b - PB_X - PB_W1 - PB_W2) * 256 + t;  // 16384 = 256k x 64h
        int k = id >> 6, h = id & 63;
        const float* wrow = W1 + (size_t)k * F1 + h * HID;
        const float* a1 = as1 + h * HID;
        const float* a2 = ad1 + h * HID;
        float s = 0.f, d = 0.f;
#pragma unroll 8
        for (int c = 0; c < HID; ++c) {
            float w = wrow[c];
            s += w * a1[c];
            d += w * a2[c];
        }
        w1s[id] = (bf16)s;
        w1d[id] = (bf16)d;
    } else {
        int e = (b - PB_TOT) * 256 + t;                 // hist
        if (e < E_TOT) {
            int d = (e < NE) ? edst[e] : (e - NE);
            atomicAdd(&counts[d], 1);
        }
    }
}

// ---------------- gemm2: BN=64, SPLITK=4, XCD-SWZ (R17 proven) -------------
// BM=128 BN=64 BK=64; XOR-swizzled LDS (0 conflicts, r4). Grid 1280 ->
// ~5 blocks/CU covers the per-K-step barrier drains (-7.6us vs 128x128).
// R21: OPERAND-SWAPPED MFMA (mfma(B,A)) -> each lane's f32x4 holds 4
// consecutive COLUMNS of one row: C-write packs to one bf16x4 (8B) store
// per tile pair — 8 stores/thread instead of 32 scalar 2B stores.
// Fragment loads unchanged (A/B frags are layout-symmetric: both read
// tile_row=lane&15, k-chunk).
__global__ __launch_bounds__(256)
void gemm2_kernel(const bf16* __restrict__ A, const bf16* __restrict__ BT,
                  bf16* __restrict__ C) {
    __shared__ bf16 As[128][64];
    __shared__ bf16 Bs[64][64];
    const int tid  = threadIdx.x;
    const int wave = tid >> 6, lane = tid & 63;
    const int quad = lane >> 4, lr = lane & 15;
    int bid = blockIdx.x;
    int xx = bid & 7, q = bid >> 3;          // q in 0..159
    int gp = q / 10; int nb = q - gp * 10;   // nb 0..9 (64-col tiles)
    int g = gp * 8 + xx;                     // 0..127 = 32 mb x 4 zb
    int mb = g >> 2, zb = g & 3;
    const int m0 = mb * 128, n0 = nb * 64;
    const int kchunk = F1 / 4;
    const int kbeg = zb * kchunk;
    const int wm = (wave >> 1) * 64;
    const int wn = (wave & 1) * 32;
    bf16* Cz = C + (size_t)zb * N_NODES * F2;

    const int srow = lane >> 3;
    const int scol = ((lane & 7) ^ srow) * 8;
    const int xk = lr & 7;

    f32x4 acc[4][2] = {};

    for (int kk = 0; kk < kchunk; kk += 64) {
        int k0 = kbeg + kk;
#pragma unroll
        for (int c = 0; c < 4; ++c) {               // A: 128 rows, 4/wave
            int r = wave * 32 + c * 8;
            async_cp16(&As[r][0], A + (size_t)(m0 + r + srow) * F1 + k0 + scol);
        }
#pragma unroll
        for (int c = 0; c < 2; ++c) {               // B: 64 rows, 2/wave
            int r = wave * 16 + c * 8;
            async_cp16(&Bs[r][0], BT + (size_t)(n0 + r + srow) * F1 + k0 + scol);
        }
        __syncthreads();

#pragma unroll
        for (int ks = 0; ks < 2; ++ks) {
            int ch = ((ks * 4 + quad) ^ xk) * 8;
            bf16x8 af[4], bfr[2];
#pragma unroll
            for (int mt = 0; mt < 4; ++mt)
                af[mt] = *(const bf16x8*)(&As[wm + mt * 16 + lr][ch]);
#pragma unroll
            for (int nt = 0; nt < 2; ++nt)
                bfr[nt] = *(const bf16x8*)(&Bs[wn + nt * 16 + lr][ch]);
#pragma unroll
            for (int mt = 0; mt < 4; ++mt)
#pragma unroll
                for (int nt = 0; nt < 2; ++nt)
                    acc[mt][nt] = __builtin_amdgcn_mfma_f32_16x16x32_bf16(
                        bfr[nt], af[mt], acc[mt][nt], 0, 0, 0);   // swapped
        }
        __syncthreads();
    }

    // D^T fragments: row = m (lane&15), 4 consecutive n at quad*4 -> 8B store
#pragma unroll
    for (int mt = 0; mt < 4; ++mt)
#pragma unroll
        for (int nt = 0; nt < 2; ++nt) {
            int row  = m0 + wm + mt * 16 + lr;
            int col0 = n0 + wn + nt * 16 + quad * 4;
            bf16x4 o;
#pragma unroll
            for (int j = 0; j < 4; ++j) o[j] = (bf16)acc[mt][nt][j];
            *(bf16x4*)(&Cz[(size_t)row * F2 + col0]) = o;
        }
}

// ------- layer-1 merged: gemm1 (1024 128x128 blocks) + gemv1 (1024) --------
// gemm half = R17's proven 128x128 form + R21 operand-swapped epilogue
// (16 x 8B stores instead of 64 x 2B scalar stores).
// gemv half (R20 proven, -7.2us): block stages w1s/w1d into the shared
// 32 KB smem (2 chunks of 128 k-rows); lanes read 2B from LDS.
__global__ __launch_bounds__(256)
void layer1_kernel(const bf16* __restrict__ xb, const bf16* __restrict__ W1T,
                   bf16* __restrict__ H1,
                   const float* __restrict__ x,
                   const bf16* __restrict__ w1s, const bf16* __restrict__ w1d,
                   float* __restrict__ a_src, float* __restrict__ a_dst) {
    __shared__ bf16 smem[2][128][64];       // 32 KB, shared by both branches
    int bid = blockIdx.x;
    const int tid = threadIdx.x;
    if (bid < 1024) {
        // ---- gemm1: H1 = xb @ W1T^T, 128x128 tile ----
        bf16 (*As)[64] = smem[0];
        bf16 (*Bs)[64] = smem[1];
        const int wave = tid >> 6, lane = tid & 63;
        const int quad = lane >> 4, lr = lane & 15;
        const int nb = bid & 31, mb = bid >> 5;
        const int m0 = mb * 128, n0 = nb * 128;
        const int wm = (wave >> 1) * 64;
        const int wn = (wave & 1) * 64;
        const int srow = lane >> 3;
        const int scol = ((lane & 7) ^ srow) * 8;
        const int xk = lr & 7;

        f32x4 acc[4][4] = {};

        for (int k0 = 0; k0 < IN_FEAT; k0 += 64) {
#pragma unroll
            for (int c = 0; c < 4; ++c) {
                int r = wave * 32 + c * 8;
                async_cp16(&As[r][0], xb  + (size_t)(m0 + r + srow) * IN_FEAT + k0 + scol);
                async_cp16(&Bs[r][0], W1T + (size_t)(n0 + r + srow) * IN_FEAT + k0 + scol);
            }
            __syncthreads();

#pragma unroll
            for (int ks = 0; ks < 2; ++ks) {
                int ch = ((ks * 4 + quad) ^ xk) * 8;
                bf16x8 af[4], bfr[4];
#pragma unroll
                for (int mt = 0; mt < 4; ++mt)
                    af[mt] = *(const bf16x8*)(&As[wm + mt * 16 + lr][ch]);
#pragma unroll
                for (int nt = 0; nt < 4; ++nt)
                    bfr[nt] = *(const bf16x8*)(&Bs[wn + nt * 16 + lr][ch]);
#pragma unroll
                for (int mt = 0; mt < 4; ++mt)
#pragma unroll
                    for (int nt = 0; nt < 4; ++nt)
                        acc[mt][nt] = __builtin_amdgcn_mfma_f32_16x16x32_bf16(
                            bfr[nt], af[mt], acc[mt][nt], 0, 0, 0);   // swapped
            }
            __syncthreads();
        }

        // D^T fragments: row = m (lane&15), 4 consecutive n -> 8B store
#pragma unroll
        for (int mt = 0; mt < 4; ++mt)
#pragma unroll
            for (int nt = 0; nt < 4; ++nt) {
                int row  = m0 + wm + mt * 16 + lr;
                int col0 = n0 + wn + nt * 16 + quad * 4;
                bf16x4 o;
#pragma unroll
                for (int j = 0; j < 4; ++j) o[j] = (bf16)acc[mt][nt][j];
                *(bf16x4*)(&H1[(size_t)row * F1 + col0]) = o;
            }
    } else {
        // ---- gemv1: a_src/a_dst dots, LDS-staged tables (R20) ----
        bf16* sws = &smem[0][0][0];          // 16 KB: 128 k-rows of w1s
        bf16* swd = &smem[1][0][0];          // 16 KB: 128 k-rows of w1d
        int wave = tid >> 6, lane = tid & 63;
        int n = (bid - 1024) * 4 + wave;
        const float* xr = x + (size_t)n * IN_FEAT;
        float s = 0.f, d = 0.f;
#pragma unroll
        for (int c = 0; c < 2; ++c) {        // two 128-k chunks
            __syncthreads();                 // protect prior chunk's readers
#pragma unroll
            for (int i = 0; i < 4; ++i) {    // 1024 bf16x8 per table, 256 thr
                int v = i * 256 + tid;
                ((bf16x8*)sws)[v] = ((const bf16x8*)w1s)[c * 1024 + v];
                ((bf16x8*)swd)[v] = ((const bf16x8*)w1d)[c * 1024 + v];
            }
            __syncthreads();
            for (int k0 = 0; k0 < 128; k0 += 4) {
                f32x4 xv = *(const f32x4*)(xr + c * 128 + k0);
#pragma unroll
                for (int j = 0; j < 4; ++j) {
                    float xs = xv[j];
                    s += xs * (float)sws[(k0 + j) * IN_HEAD + lane];
                    d += xs * (float)swd[(k0 + j) * IN_HEAD + lane];
                }
            }
        }
        a_src[n * IN_HEAD + lane] = s;
        a_dst[n * IN_HEAD + lane] = d;
    }
}

// ------- layer-1 aggregation, FEATURE-SLICED + XCD-PINNED ------------------
// grid = 4096 dst x 8 slices, 64 threads (1 wave). bid&7 = slice -> XCD:
// XCD x only touches H1 cols [512x,512x+512) = 4 MB = its L2 capacity.
// R9: single-pass online softmax (defer-rescale T13).
// R10: software pipeline broke the per-edge latency chain (47->~30us WIN).
// R11: srclist (2-level chain). R12: depth-4 a_src/H1, slack-2 srclist.
// Explicit named rotation regs (rule #20).
__global__ __launch_bounds__(64)
void agg1_kernel(const int* __restrict__ row_start,
                 const int* __restrict__ srclist,
                 const float* __restrict__ a_src, const float* __restrict__ a_dst,
                 const bf16* __restrict__ H1, const float* __restrict__ b1,
                 bf16* __restrict__ h_elu) {
    int bid = blockIdx.x;
    int c = bid & 7;            // feature slice / XCD
    int d = bid >> 3;           // dst node
    int lane = threadIdx.x;
    int gh = c * 8 + (lane >> 3);   // global head for this lane
    int beg = row_start[d], deg = row_start[d + 1] - beg;
    float adst = a_dst[d * IN_HEAD + gh];
    int fbase = c * 512 + lane * 8;
    const float* asg = a_src + gh;

    // clamped prefetch (deg >= 1 always; repeats hit L1/L2, harmless)
    auto SL = [&](int i) { return srclist[beg + (i < deg ? i : deg - 1)]; };

    // ---- pipeline prologue: 4 la/v stages in flight, 2 s-regs of slack ----
    int s0 = SL(0), s1 = SL(1), s2 = SL(2), s3 = SL(3);
    float la0 = asg[(size_t)s0 * IN_HEAD];
    bf16x8 v0 = *(const bf16x8*)(H1 + (size_t)s0 * F1 + fbase);
    float la1 = asg[(size_t)s1 * IN_HEAD];
    bf16x8 v1 = *(const bf16x8*)(H1 + (size_t)s1 * F1 + fbase);
    float la2 = asg[(size_t)s2 * IN_HEAD];
    bf16x8 v2 = *(const bf16x8*)(H1 + (size_t)s2 * F1 + fbase);
    float la3 = asg[(size_t)s3 * IN_HEAD];
    bf16x8 v3 = *(const bf16x8*)(H1 + (size_t)s3 * F1 + fbase);
    int s4 = SL(4), s5 = SL(5);

    float m = -1e30f, den = 0.f;
    float acc[8] = {};
    for (int i = 0; i < deg; ++i) {
        // stage issues (independent of this iteration's compute):
        int sn = SL(i + 6);                              // srclist, slack 2
        float la4 = asg[(size_t)s4 * IN_HEAD];           // edge i+4
        bf16x8 v4 = *(const bf16x8*)(H1 + (size_t)s4 * F1 + fbase);

        // compute edge i (operands loaded 4 iterations ago)
        float l = la0 + adst;
        l = l > 0.f ? l : NEG_SLOPE * l;
        if (l > m + 12.f) {                  // deferred rescale (rare)
            float r = __expf(m - l);         // m=-1e30 -> r=0 zeroes init
            den *= r;
#pragma unroll
            for (int k = 0; k < 8; ++k) acc[k] *= r;
            m = l;
        }
        float w = __expf(l - m);             // bounded by e^12
        den += w;
#pragma unroll
        for (int k = 0; k < 8; ++k) acc[k] += w * (float)v0[k];

        // rotate pipeline registers
        la0 = la1; v0 = v1;
        la1 = la2; v1 = v2;
        la2 = la3; v2 = v3;
        la3 = la4; v3 = v4;
        s4 = s5; s5 = sn;
    }
    float dinv = 1.f / (den + EPS_A);

    bf16x8 o;
#pragma unroll
    for (int j = 0; j < 8; ++j) {
        float v = acc[j] * dinv + b1[fbase + j];
        o[j] = (bf16)(v > 0.f ? v : (__expf(v) - 1.f));   // ELU
    }
    *(bf16x8*)(h_elu + (size_t)d * F1 + fbase) = o;
}

// ------- fold 4 bf16 z-partials -> H2 fp32, fused att2 dots ----------------
__global__ __launch_bounds__(192)
void fold2_kernel(const bf16* __restrict__ Hp,
                  const float* __restrict__ as2, const float* __restrict__ ad2,
                  float* __restrict__ H2,
                  float* __restrict__ a_src, float* __restrict__ a_dst) {
    int n = blockIdx.x, t = threadIdx.x;
    if (t >= 160) return;
    int h = t >> 5;
    f32x4 sum = {};
#pragma unroll
    for (int z = 0; z < 4; ++z) {
        bf16x4 v = *(const bf16x4*)(Hp + (size_t)z * N_NODES * F2 + (size_t)n * F2 + t * 4);
        sum[0] += (float)v[0]; sum[1] += (float)v[1];
        sum[2] += (float)v[2]; sum[3] += (float)v[3];
    }
    *(f32x4*)(H2 + (size_t)n * F2 + t * 4) = sum;
    f32x4 ws = *(const f32x4*)(as2 + t * 4);
    f32x4 wd = *(const f32x4*)(ad2 + t * 4);
    float s = sum[0] * ws[0] + sum[1] * ws[1] + sum[2] * ws[2] + sum[3] * ws[3];
    float d = sum[0] * wd[0] + sum[1] * wd[1] + sum[2] * wd[2] + sum[3] * wd[3];
#pragma unroll
    for (int o = 1; o <= 16; o <<= 1) {
        s += __shfl_xor(s, o);
        d += __shfl_xor(d, o);
    }
    if ((t & 31) == 0) {
        a_src[n * OUT_HEAD + h] = s;
        a_dst[n * OUT_HEAD + h] = d;
    }
}

// ------- layer-2 softmax stats: thread per (dst,head) over CSR ----------
// defer-rescale (exact — offset cancels in beta) + depth-2 prefetch;
// zeroes beta[id] (replaces memset; runs before beta_kernel). [R13, kept]
__global__ void stats2_kernel(const int* __restrict__ row_start,
                              const int* __restrict__ srclist,
                              const float* __restrict__ a_src,
                              const float* __restrict__ a_dst,
                              float* __restrict__ m2, float* __restrict__ dinv2,
                              float* __restrict__ beta) {
    int id = blockIdx.x * 256 + threadIdx.x;
    if (id >= N_NODES * OUT_HEAD) return;
    beta[id] = 0.f;
    int d = id / OUT_HEAD, h = id - d * OUT_HEAD;
    int beg = row_start[d], deg = row_start[d + 1] - beg;
    float adst = a_dst[id];
    auto SL = [&](int i) { return srclist[beg + (i < deg ? i : deg - 1)]; };
    int s0 = SL(0), s1 = SL(1);
    float la0 = a_src[s0 * OUT_HEAD + h];
    float m = -1e30f, den = 0.f;
    for (int i = 0; i < deg; ++i) {
        int s2 = SL(i + 2);
        float la1 = a_src[s1 * OUT_HEAD + h];
        float l = la0 + adst;
        l = l > 0.f ? l : NEG_SLOPE * l;
        if (l > m + 12.f) { den *= __expf(m - l); m = l; }
        den += __expf(l - m);
        la0 = la1; s1 = s2;
    }
    m2[id] = m;
    dinv2[id] = 1.f / (den + EPS_A);
}

// ------- beta[s][h] = sum over edges with src s of alpha2[e][h] ----------
// edge-parallel (184k threads). Also zeroes acc_out/ticket for wsum
// (stream order guarantees completion before wsum launches). [R13, kept]
__global__ void beta_kernel(const int* __restrict__ es, const int* __restrict__ ed,
                            const float* __restrict__ a_src, const float* __restrict__ a_dst,
                            const float* __restrict__ m2, const float* __restrict__ dinv2,
                            float* __restrict__ beta,
                            float* __restrict__ acc_out, int* __restrict__ ticket) {
    int id = blockIdx.x * 256 + threadIdx.x;
    if (id < 8 * OUT_FEAT) acc_out[id] = 0.f;
    else if (id == 8 * OUT_FEAT) *ticket = 0;
    if (id >= E_TOT * OUT_HEAD) return;
    int e = id / OUT_HEAD, h = id - e * OUT_HEAD;
    int s = (e < NE) ? es[e] : (e - NE);
    int d = (e < NE) ? ed[e] : (e - NE);
    float l = a_src[s * OUT_HEAD + h] + a_dst[d * OUT_HEAD + h];
    l = l > 0.f ? l : NEG_SLOPE * l;
    float alpha = __expf(l - m2[d * OUT_HEAD + h]) * dinv2[d * OUT_HEAD + h];
    atomicAdd(&beta[s * OUT_HEAD + h], alpha);
}

// ------- total[c] = sum_s sum_h beta[s,h]H2[s,h*128+c]; 8-way stripes -------
// tanh fused via last-block ticket (device-scope atomics; coherent cross-XCD
// readback via atomicAdd(p, 0.f) — G16-safe). Verified R12.
__global__ __launch_bounds__(256)
void wsum_kernel(const float* __restrict__ H2, const float* __restrict__ beta,
                 float* __restrict__ acc_out, const float* __restrict__ b2,
                 float* __restrict__ out, int* __restrict__ ticket) {
    __shared__ float buf[F2];
    __shared__ int lastblk;
    int t = threadIdx.x;
    int n0 = blockIdx.x * 32;
    int h = t >> 5;
    float a0 = 0.f, a1 = 0.f, a2 = 0.f, a3 = 0.f;
    if (t < 160) {
        for (int i = 0; i < 32; ++i) {
            int s = n0 + i;
            float bh = beta[s * OUT_HEAD + h];
            f32x4 v = *(const f32x4*)(H2 + (size_t)s * F2 + t * 4);
            a0 += bh * v[0]; a1 += bh * v[1];
            a2 += bh * v[2]; a3 += bh * v[3];
        }
        buf[t * 4 + 0] = a0; buf[t * 4 + 1] = a1;
        buf[t * 4 + 2] = a2; buf[t * 4 + 3] = a3;
    }
    __syncthreads();
    if (t < OUT_FEAT) {
        float s = 0.f;
#pragma unroll
        for (int hh = 0; hh < OUT_HEAD; ++hh) s += buf[hh * OUT_FEAT + t];
        atomicAdd(&acc_out[(blockIdx.x & 7) * OUT_FEAT + t], s);
    }
    __syncthreads();                      // barrier drains this block's atomics
    if (t == 0) {
        __threadfence();
        lastblk = (atomicAdd(ticket, 1) == (int)gridDim.x - 1);
    }
    __syncthreads();
    if (lastblk && t < OUT_FEAT) {
        float tot = 0.f;
#pragma unroll
        for (int k = 0; k < 8; ++k)
            tot += atomicAdd(&acc_out[k * OUT_FEAT + t], 0.0f);  // coherent read
        out[t] = tanhf(tot * (1.f / (OUT_HEAD * (float)N_NODES)) + b2[t]);
    }
}

// ---------------- launch ----------------
extern "C" void kernel_launch(void* const* d_in, const int* in_sizes, int n_in,
                              void* d_out, int out_size, void* d_ws, size_t ws_size,
                              hipStream_t stream) {
    const float* x        = (const float*)d_in[0];
    const int*   ei       = (const int*)d_in[1];
    const float* W1       = (const float*)d_in[2];
    const float* att_src1 = (const float*)d_in[3];
    const float* att_dst1 = (const float*)d_in[4];
    const float* b1       = (const float*)d_in[5];
    const float* W2       = (const float*)d_in[6];
    const float* att_src2 = (const float*)d_in[7];
    const float* att_dst2 = (const float*)d_in[8];
    const float* b2       = (const float*)d_in[9];
    float* out = (float*)d_out;

    const int* esrc = ei;
    const int* edst = ei + NE;

    // workspace carve (~110 MB)
    char* p = (char*)d_ws;
    auto bump = [&](size_t bytes) {
        void* r = (void*)p;
        p += (bytes + 255) & ~(size_t)255;
        return r;
    };
    bf16*  H1     = (bf16*)bump((size_t)N_NODES * F1 * 2);        // 32 MB
    bf16*  h_elu  = (bf16*)bump((size_t)N_NODES * F1 * 2);        // 32 MB
    bf16*  Hp     = (bf16*)bump((size_t)4 * N_NODES * F2 * 2);    // 21 MB (4 z-partials)
    float* H2     = (float*)bump((size_t)N_NODES * F2 * 4);       // 10.5 MB
    bf16*  xb     = (bf16*)bump((size_t)N_NODES * IN_FEAT * 2);   // 2 MB
    bf16*  W1T    = (bf16*)bump((size_t)F1 * IN_FEAT * 2);        // 2 MB
    bf16*  W2T    = (bf16*)bump((size_t)F2 * F1 * 2);             // 5 MB
    bf16*  w1s    = (bf16*)bump((size_t)IN_FEAT * IN_HEAD * 2);
    bf16*  w1d    = (bf16*)bump((size_t)IN_FEAT * IN_HEAD * 2);
    float* a_src1 = (float*)bump((size_t)N_NODES * IN_HEAD * 4);
    float* a_dst1 = (float*)bump((size_t)N_NODES * IN_HEAD * 4);
    float* a_src2 = (float*)bump((size_t)N_NODES * OUT_HEAD * 4);
    float* a_dst2 = (float*)bump((size_t)N_NODES * OUT_HEAD * 4);
    float* m2     = (float*)bump((size_t)N_NODES * OUT_HEAD * 4);
    float* dinv2  = (float*)bump((size_t)N_NODES * OUT_HEAD * 4);
    int*   row_start = (int*)bump((N_NODES + 1) * 4);
    int*   cursor  = (int*)bump(N_NODES * 4);
    int*   srclist = (int*)bump(E_TOT * 4);
    int*   counts  = (int*)bump(N_NODES * 4);
    float* beta    = (float*)bump((size_t)N_NODES * OUT_HEAD * 4);
    float* acc_out = (float*)bump((size_t)8 * OUT_FEAT * 4);
    int*   ticket  = (int*)bump(4);

    // counts zero (16 KB) then prep(+hist) -> scan -> scatter
    hipMemsetAsync(counts, 0, N_NODES * 4, stream);
    prep_kernel<<<PB_TOT + PB_HIST, 256, 0, stream>>>(
        x, xb, W1, W1T, W2, W2T, att_src1, att_dst1, w1s, w1d, edst, counts);
    scan_kernel<<<1, 256, 0, stream>>>(counts, row_start, cursor);
    scatter_kernel<<<(E_TOT + 255) / 256, 256, 0, stream>>>(
        esrc, edst, cursor, srclist);

    // layer 1: gemm1 (128x128, 1024 blocks) + gemv1 (LDS-staged, 1024)
    layer1_kernel<<<2048, 256, 0, stream>>>(
        xb, W1T, H1, x, w1s, w1d, a_src1, a_dst1);
    agg1_kernel<<<N_NODES * 8, 64, 0, stream>>>(
        row_start, srclist, a_src1, a_dst1, H1, b1, h_elu);

    // layer 2: BN=64 SPLITK=4 z-partials (grid 1280, ~5 blocks/CU) + fold
    gemm2_kernel<<<1280, 256, 0, stream>>>(h_elu, W2T, Hp);
    fold2_kernel<<<N_NODES, 192, 0, stream>>>(
        Hp, att_src2, att_dst2, H2, a_src2, a_dst2);
    stats2_kernel<<<(N_NODES * OUT_HEAD + 255) / 256, 256, 0, stream>>>(
        row_start, srclist, a_src2, a_dst2, m2, dinv2, beta);
    beta_kernel<<<(E_TOT * OUT_HEAD + 255) / 256, 256, 0, stream>>>(
        esrc, edst, a_src2, a_dst2, m2, dinv2, beta, acc_out, ticket);
    wsum_kernel<<<N_NODES / 32, 256, 0, stream>>>(
        H2, beta, acc_out, b2, out, ticket);
}